// Round 3
// baseline (455.929 us; speedup 1.0000x reference)
//
#include <hip/hip_runtime.h>

// Problem constants (from reference setup_inputs)
constexpr int B  = 16;
constexpr int C  = 3;
constexpr int H  = 768;
constexpr int W  = 1024;
constexpr int HW = H * W;

// 8-byte vector with 4-byte alignment: lets the gather pair (x0,x0+1) be one
// (or at worst two coalesced) VMEM op(s) without alignment UB.
typedef float f2 __attribute__((ext_vector_type(2), aligned(4)));
typedef float f4 __attribute__((ext_vector_type(4)));

// Fused: bilinear backwarp(second, flow) -> |first - warped| -> mean_C -> *alpha
// 4 pixels per thread (row-aligned), float4 streaming IO, dwordx2 gathers.
// NOTE: no non-temporal hints — the harness's per-launch input restore leaves
// d_in hot in L2/L3; NT hints forced real HBM traffic (R2: FETCH 285->595 MB).
__global__ __launch_bounds__(256) void warp_l1_mean_v3(
    const float* __restrict__ first,
    const float* __restrict__ second,
    const float* __restrict__ flow,
    const float* __restrict__ alpha,
    float* __restrict__ out)
{
    const int b = blockIdx.y;
    const int p = (blockIdx.x * 256 + (int)threadIdx.x) * 4;  // pixel base within plane
    const int y  = p >> 10;        // W = 1024
    const int xb = p & (W - 1);

    const float* fl  = flow   + (size_t)b * 2 * HW;
    const float* fst = first  + (size_t)b * C * HW;
    const float* sec = second + (size_t)b * C * HW;

    const f4 fx = *(const f4*)(fl + p);
    const f4 fy = *(const f4*)(fl + HW + p);

    int   row0[4], row1[4];
    int   off0[4], off1[4];
    float hx0[4], hx1[4], gy0[4], gy1[4];

#pragma unroll
    for (int i = 0; i < 4; ++i) {
        const float ix = (float)(xb + i) + fx[i] * ((float)W / (float)(W - 1));
        const float iy = (float)y        + fy[i] * ((float)H / (float)(H - 1));
        const float x0f = floorf(ix);
        const float y0f = floorf(iy);
        const float wx1 = ix - x0f;
        const float wy1 = iy - y0f;

        const int x0  = (int)x0f;
        const int y0i = (int)y0f;
        const int x1  = x0 + 1;
        const int y1  = y0i + 1;

        // pair base clamped so [bx, bx+1] stays inside the row
        const int bx = min(max(x0, 0), W - 2);
        off0[i] = min(max(x0 - bx, 0), 1);
        off1[i] = min(max(x1 - bx, 0), 1);

        const float vx0 = ((unsigned)x0  < (unsigned)W) ? 1.0f : 0.0f;
        const float vx1 = ((unsigned)x1  < (unsigned)W) ? 1.0f : 0.0f;
        const float vy0 = ((unsigned)y0i < (unsigned)H) ? 1.0f : 0.0f;
        const float vy1 = ((unsigned)y1  < (unsigned)H) ? 1.0f : 0.0f;

        hx0[i] = (1.0f - wx1) * vx0;
        hx1[i] = wx1 * vx1;
        gy0[i] = (1.0f - wy1) * vy0;
        gy1[i] = wy1 * vy1;

        const int cy0 = min(max(y0i, 0), H - 1);
        const int cy1 = min(max(y1,  0), H - 1);
        row0[i] = cy0 * W + bx;
        row1[i] = cy1 * W + bx;
    }

    const f4 a0 = *(const f4*)(fst + p);
    const f4 a1 = *(const f4*)(fst + HW + p);
    const f4 a2 = *(const f4*)(fst + 2 * HW + p);

    f4 acc = {0.0f, 0.0f, 0.0f, 0.0f};

#pragma unroll
    for (int c = 0; c < C; ++c) {
        const float* s = sec + c * HW;
#pragma unroll
        for (int i = 0; i < 4; ++i) {
            const f2 v0 = *(const f2*)(s + row0[i]);
            const f2 v1 = *(const f2*)(s + row1[i]);
            const float t00 = off0[i] ? v0.y : v0.x;
            const float t01 = off1[i] ? v0.y : v0.x;
            const float t10 = off0[i] ? v1.y : v1.x;
            const float t11 = off1[i] ? v1.y : v1.x;
            const float warped = gy0[i] * (hx0[i] * t00 + hx1[i] * t01)
                               + gy1[i] * (hx0[i] * t10 + hx1[i] * t11);
            const float af = (c == 0) ? a0[i] : (c == 1) ? a1[i] : a2[i];
            acc[i] += fabsf(af - warped);
        }
    }

    const float s = alpha[0] * (1.0f / 3.0f);
    f4 r;
    r.x = acc.x * s; r.y = acc.y * s; r.z = acc.z * s; r.w = acc.w * s;
    *(f4*)(out + (size_t)b * HW + p) = r;
}

extern "C" void kernel_launch(void* const* d_in, const int* in_sizes, int n_in,
                              void* d_out, int out_size, void* d_ws, size_t ws_size,
                              hipStream_t stream) {
    const float* first  = (const float*)d_in[0];
    const float* second = (const float*)d_in[1];
    const float* flow   = (const float*)d_in[2];
    const float* alpha  = (const float*)d_in[3];
    float* out = (float*)d_out;

    // 4 pixels/thread, 256 threads/block: HW/(4*256) = 768 blocks per batch
    dim3 grid(HW / (4 * 256), B);
    warp_l1_mean_v3<<<grid, dim3(256), 0, stream>>>(first, second, flow, alpha, out);
}

// Round 4
// 431.587 us; speedup vs baseline: 1.0564x; 1.0564x over previous
//
#include <hip/hip_runtime.h>

// Problem constants (from reference setup_inputs)
constexpr int B  = 16;
constexpr int C  = 3;
constexpr int H  = 768;
constexpr int W  = 1024;
constexpr int HW = H * W;

typedef float f2 __attribute__((ext_vector_type(2), aligned(4)));
typedef float f4 __attribute__((ext_vector_type(4)));

// Fused: bilinear backwarp(second, flow) -> |first - warped| -> mean_C -> *alpha
// 4 pixels/thread (one block = one image row), f2 gathers, f4 IO.
// XCD band swizzle: HW assigns blocks to XCDs round-robin (blockIdx.x % 8).
// Map XCD k to rows [96k, 96k+96) so the vertical second-row reuse (the only
// reuse in this kernel) stays inside one XCD's L2 and is temporally adjacent.
// (R3 post-mortem: row-per-block without swizzle put rows y and y+1 on
// different XCDs -> second fetched into 2 L2s -> FETCH 285->620 MB.)
__global__ __launch_bounds__(256) void warp_l1_mean_v4(
    const float* __restrict__ first,
    const float* __restrict__ second,
    const float* __restrict__ flow,
    const float* __restrict__ alpha,
    float* __restrict__ out)
{
    constexpr int ROWS_PER_XCD = H / 8;  // 96

    const int b   = blockIdx.y;
    const int xcd = blockIdx.x & 7;
    const int seq = blockIdx.x >> 3;
    const int y   = xcd * ROWS_PER_XCD + seq;

    const int xb = (int)threadIdx.x * 4;
    const int p  = y * W + xb;

    const float* fl  = flow   + (size_t)b * 2 * HW;
    const float* fst = first  + (size_t)b * C * HW;
    const float* sec = second + (size_t)b * C * HW;

    const f4 fx = *(const f4*)(fl + p);
    const f4 fy = *(const f4*)(fl + HW + p);

    int   row0[4], row1[4];
    int   off0[4], off1[4];
    float hx0[4], hx1[4], gy0[4], gy1[4];

#pragma unroll
    for (int i = 0; i < 4; ++i) {
        const float ix = (float)(xb + i) + fx[i] * ((float)W / (float)(W - 1));
        const float iy = (float)y        + fy[i] * ((float)H / (float)(H - 1));
        const float x0f = floorf(ix);
        const float y0f = floorf(iy);
        const float wx1 = ix - x0f;
        const float wy1 = iy - y0f;

        const int x0  = (int)x0f;
        const int y0i = (int)y0f;
        const int x1  = x0 + 1;
        const int y1  = y0i + 1;

        // pair base clamped so [bx, bx+1] stays inside the row
        const int bx = min(max(x0, 0), W - 2);
        off0[i] = min(max(x0 - bx, 0), 1);
        off1[i] = min(max(x1 - bx, 0), 1);

        const float vx0 = ((unsigned)x0  < (unsigned)W) ? 1.0f : 0.0f;
        const float vx1 = ((unsigned)x1  < (unsigned)W) ? 1.0f : 0.0f;
        const float vy0 = ((unsigned)y0i < (unsigned)H) ? 1.0f : 0.0f;
        const float vy1 = ((unsigned)y1  < (unsigned)H) ? 1.0f : 0.0f;

        hx0[i] = (1.0f - wx1) * vx0;
        hx1[i] = wx1 * vx1;
        gy0[i] = (1.0f - wy1) * vy0;
        gy1[i] = wy1 * vy1;

        const int cy0 = min(max(y0i, 0), H - 1);
        const int cy1 = min(max(y1,  0), H - 1);
        row0[i] = cy0 * W + bx;
        row1[i] = cy1 * W + bx;
    }

    const f4 a0 = *(const f4*)(fst + p);
    const f4 a1 = *(const f4*)(fst + HW + p);
    const f4 a2 = *(const f4*)(fst + 2 * HW + p);

    f4 acc = {0.0f, 0.0f, 0.0f, 0.0f};

#pragma unroll
    for (int c = 0; c < C; ++c) {
        const float* s = sec + c * HW;
#pragma unroll
        for (int i = 0; i < 4; ++i) {
            const f2 v0 = *(const f2*)(s + row0[i]);
            const f2 v1 = *(const f2*)(s + row1[i]);
            const float t00 = off0[i] ? v0.y : v0.x;
            const float t01 = off1[i] ? v0.y : v0.x;
            const float t10 = off0[i] ? v1.y : v1.x;
            const float t11 = off1[i] ? v1.y : v1.x;
            const float warped = gy0[i] * (hx0[i] * t00 + hx1[i] * t01)
                               + gy1[i] * (hx0[i] * t10 + hx1[i] * t11);
            const float af = (c == 0) ? a0[i] : (c == 1) ? a1[i] : a2[i];
            acc[i] += fabsf(af - warped);
        }
    }

    const float s = alpha[0] * (1.0f / 3.0f);
    f4 r;
    r.x = acc.x * s; r.y = acc.y * s; r.z = acc.z * s; r.w = acc.w * s;
    *(f4*)(out + (size_t)b * HW + p) = r;
}

extern "C" void kernel_launch(void* const* d_in, const int* in_sizes, int n_in,
                              void* d_out, int out_size, void* d_ws, size_t ws_size,
                              hipStream_t stream) {
    const float* first  = (const float*)d_in[0];
    const float* second = (const float*)d_in[1];
    const float* flow   = (const float*)d_in[2];
    const float* alpha  = (const float*)d_in[3];
    float* out = (float*)d_out;

    // one block per image row; grid.x = 768 rows, grid.y = 16 batches
    dim3 grid(H, B);
    warp_l1_mean_v4<<<grid, dim3(256), 0, stream>>>(first, second, flow, alpha, out);
}